// Round 1
// baseline (2704.285 us; speedup 1.0000x reference)
//
#include <hip/hip_runtime.h>

#define D 64
#define NEG_INF -9e15f
#define MAXK 16

// ---------- Phase 0: relation-space precompute ----------
// w1r[r][j] = sum_d fc_W[j][d]      * rel[r][d]
// w2r[r][j] = sum_d fc_W[64+j][d]   * rel[r][d]
// br[r]     = sum_d fc_b[d]         * rel[r][d]
__global__ void relpre_kernel(const float* __restrict__ fc_W, const float* __restrict__ fc_b,
                              const float* __restrict__ rel_emb,
                              float* __restrict__ w1r, float* __restrict__ w2r,
                              float* __restrict__ br) {
    int r = blockIdx.x;
    int j = threadIdx.x;
    const float* rr = rel_emb + r * D;
    float s1 = 0.f, s2 = 0.f;
    for (int d = 0; d < D; ++d) {
        float rv = rr[d];
        s1 += fc_W[j * D + d] * rv;
        s2 += fc_W[(D + j) * D + d] * rv;
    }
    w1r[r * D + j] = s1;
    w2r[r * D + j] = s2;
    if (j == 0) {
        float sb = 0.f;
        for (int d = 0; d < D; ++d) sb += fc_b[d] * rr[d];
        br[r] = sb;
    }
}

// ---------- Phase 1: GAT item embeddings ----------
// One 64-lane wave per item. Lane = feature d.
__global__ void gat_kernel(const float* __restrict__ item_emb, const float* __restrict__ ent_emb,
                           const int* __restrict__ kg_e, const int* __restrict__ kg_r,
                           const float* __restrict__ w1r, const float* __restrict__ w2r,
                           const float* __restrict__ br,
                           float* __restrict__ x_items, int I, int K, int pad_id) {
    int wave = (blockIdx.x * blockDim.x + threadIdx.x) >> 6;
    int lane = threadIdx.x & 63;
    if (wave >= I) return;
    int i = wave;
    float itemv = item_emb[i * D + lane];
    float entv[MAXK];
    float e[MAXK];
    for (int k = 0; k < K; ++k) {
        int eidx = kg_e[i * K + k];
        int r = kg_r[i * K + k];
        float ev = ent_emb[(long)eidx * D + lane];
        entv[k] = ev;
        float p = itemv * w1r[r * D + lane] + ev * w2r[r * D + lane];
        #pragma unroll
        for (int off = 32; off > 0; off >>= 1) p += __shfl_xor(p, off, 64);
        p += br[r];
        p = p > 0.f ? p : 0.2f * p;          // leaky relu
        if (eidx == pad_id) p = NEG_INF;      // padding mask
        e[k] = p;
    }
    // softmax over K (all lanes hold identical e[k])
    float m = e[0];
    for (int k = 1; k < K; ++k) m = fmaxf(m, e[k]);
    float s = 0.f;
    float att[MAXK];
    for (int k = 0; k < K; ++k) { att[k] = expf(e[k] - m); s += att[k]; }
    float inv = 1.f / s;
    float o = itemv;                          // residual
    for (int k = 0; k < K; ++k) o += att[k] * inv * entv[k];
    x_items[(long)i * D + lane] = o;
}

// ---------- Phase 2a: init x (user part) and acc = x ----------
__global__ void init_kernel(const float* __restrict__ user_emb,
                            float* __restrict__ x, float* __restrict__ acc,
                            int UD, int ND) {
    for (int idx = blockIdx.x * blockDim.x + threadIdx.x; idx < ND;
         idx += gridDim.x * blockDim.x) {
        float v = (idx < UD) ? user_emb[idx] : x[idx];
        x[idx] = v;
        acc[idx] = v;
    }
}

// ---------- Phase 2b: edge scatter: y[row] += val * x[col] ----------
// One wave per edge; lane = feature.
__global__ void scatter_kernel(const int* __restrict__ rows, const int* __restrict__ cols,
                               const float* __restrict__ vals,
                               const float* __restrict__ x, float* __restrict__ y,
                               int n_edges) {
    long gid = (long)blockIdx.x * blockDim.x + threadIdx.x;
    int e = (int)(gid >> 6);
    if (e >= n_edges) return;
    int d = (int)(gid & 63);
    int row = rows[e];
    int col = cols[e];
    float v = vals[e];
    unsafeAtomicAdd(&y[(long)row * D + d], v * x[(long)col * D + d]);
}

// ---------- Phase 2c: acc += y ----------
__global__ void accadd_kernel(float* __restrict__ acc, const float* __restrict__ y, int ND) {
    for (int idx = blockIdx.x * blockDim.x + threadIdx.x; idx < ND;
         idx += gridDim.x * blockDim.x) {
        acc[idx] += y[idx];
    }
}

// ---------- Phase 3: gamma[b] = dot(light[u], light[U+i]) ----------
__global__ void dot_kernel(const float* __restrict__ acc,
                           const int* __restrict__ users, const int* __restrict__ items,
                           float* __restrict__ out, int U, int B) {
    int wave = (blockIdx.x * blockDim.x + threadIdx.x) >> 6;
    int lane = threadIdx.x & 63;
    if (wave >= B) return;
    int u = users[wave];
    int it = items[wave];
    float p = acc[(long)u * D + lane] * acc[(long)(U + it) * D + lane];
    #pragma unroll
    for (int off = 32; off > 0; off >>= 1) p += __shfl_xor(p, off, 64);
    if (lane == 0) out[wave] = p * 0.0625f;   // (acc/4)·(acc/4) = dot/16
}

extern "C" void kernel_launch(void* const* d_in, const int* in_sizes, int n_in,
                              void* d_out, int out_size, void* d_ws, size_t ws_size,
                              hipStream_t stream) {
    const int*   users    = (const int*)  d_in[0];
    const int*   items    = (const int*)  d_in[1];
    const int*   g_rows   = (const int*)  d_in[2];
    const int*   g_cols   = (const int*)  d_in[3];
    const float* g_vals   = (const float*)d_in[4];
    const float* user_emb = (const float*)d_in[5];
    const float* item_emb = (const float*)d_in[6];
    const float* ent_emb  = (const float*)d_in[7];
    const float* rel_emb  = (const float*)d_in[8];
    const int*   kg_e     = (const int*)  d_in[9];
    const int*   kg_r     = (const int*)  d_in[10];
    const float* fc_W     = (const float*)d_in[11];
    const float* fc_b     = (const float*)d_in[12];
    float* out = (float*)d_out;

    int B       = in_sizes[0];
    int n_edges = in_sizes[2];
    int U       = in_sizes[5] / D;
    int I       = in_sizes[6] / D;
    int NE1     = in_sizes[7] / D;   // E_ENT + 1
    int NR      = in_sizes[8] / D;   // R + 1
    int K       = in_sizes[9] / I;
    int N  = U + I;
    int ND = N * D;

    float* ws  = (float*)d_ws;
    float* x   = ws;                 // [N*D]
    float* y   = ws + (long)ND;      // [N*D]
    float* acc = ws + 2L * ND;       // [N*D]
    float* w1r = ws + 3L * ND;       // [NR*D]
    float* w2r = w1r + (long)NR * D; // [NR*D]
    float* br  = w2r + (long)NR * D; // [NR]

    // Phase 0: relation precompute
    relpre_kernel<<<NR, D, 0, stream>>>(fc_W, fc_b, rel_emb, w1r, w2r, br);

    // Phase 1: GAT item embeddings -> item part of x
    gat_kernel<<<(I + 3) / 4, 256, 0, stream>>>(item_emb, ent_emb, kg_e, kg_r,
                                                w1r, w2r, br,
                                                x + (long)U * D, I, K, NE1 - 1);

    // Phase 2: LightGCN, 3 layers
    init_kernel<<<2048, 256, 0, stream>>>(user_emb, x, acc, U * D, ND);

    float* cur = x;
    float* nxt = y;
    for (int l = 0; l < 3; ++l) {
        hipMemsetAsync(nxt, 0, (size_t)ND * sizeof(float), stream);
        long total = (long)n_edges * 64;
        int blocks = (int)((total + 255) / 256);
        scatter_kernel<<<blocks, 256, 0, stream>>>(g_rows, g_cols, g_vals, cur, nxt, n_edges);
        accadd_kernel<<<2048, 256, 0, stream>>>(acc, nxt, ND);
        float* t = cur; cur = nxt; nxt = t;
    }

    // Phase 3: batch dot
    dot_kernel<<<(B + 3) / 4, 256, 0, stream>>>(acc, users, items, out, U, B);
}

// Round 2
// 997.342 us; speedup vs baseline: 2.7115x; 2.7115x over previous
//
#include <hip/hip_runtime.h>

#define D 64
#define NEG_INF -9e15f
#define MAXK 16

// ---------- Phase 0: relation-space precompute ----------
__global__ void relpre_kernel(const float* __restrict__ fc_W, const float* __restrict__ fc_b,
                              const float* __restrict__ rel_emb,
                              float* __restrict__ w1r, float* __restrict__ w2r,
                              float* __restrict__ br) {
    int r = blockIdx.x;
    int j = threadIdx.x;
    const float* rr = rel_emb + r * D;
    float s1 = 0.f, s2 = 0.f;
    for (int d = 0; d < D; ++d) {
        float rv = rr[d];
        s1 += fc_W[j * D + d] * rv;
        s2 += fc_W[(D + j) * D + d] * rv;
    }
    w1r[r * D + j] = s1;
    w2r[r * D + j] = s2;
    if (j == 0) {
        float sb = 0.f;
        for (int d = 0; d < D; ++d) sb += fc_b[d] * rr[d];
        br[r] = sb;
    }
}

// ---------- Phase 1: GAT item embeddings (one wave per item) ----------
__global__ void gat_kernel(const float* __restrict__ item_emb, const float* __restrict__ ent_emb,
                           const int* __restrict__ kg_e, const int* __restrict__ kg_r,
                           const float* __restrict__ w1r, const float* __restrict__ w2r,
                           const float* __restrict__ br,
                           float* __restrict__ x_items, int I, int K, int pad_id) {
    int wave = (blockIdx.x * blockDim.x + threadIdx.x) >> 6;
    int lane = threadIdx.x & 63;
    if (wave >= I) return;
    int i = wave;
    float itemv = item_emb[i * D + lane];
    float entv[MAXK];
    float e[MAXK];
    for (int k = 0; k < K; ++k) {
        int eidx = kg_e[i * K + k];
        int r = kg_r[i * K + k];
        float ev = ent_emb[(long)eidx * D + lane];
        entv[k] = ev;
        float p = itemv * w1r[r * D + lane] + ev * w2r[r * D + lane];
        #pragma unroll
        for (int off = 32; off > 0; off >>= 1) p += __shfl_xor(p, off, 64);
        p += br[r];
        p = p > 0.f ? p : 0.2f * p;
        if (eidx == pad_id) p = NEG_INF;
        e[k] = p;
    }
    float m = e[0];
    for (int k = 1; k < K; ++k) m = fmaxf(m, e[k]);
    float s = 0.f;
    float att[MAXK];
    for (int k = 0; k < K; ++k) { att[k] = expf(e[k] - m); s += att[k]; }
    float inv = 1.f / s;
    float o = itemv;
    for (int k = 0; k < K; ++k) o += att[k] * inv * entv[k];
    x_items[(long)i * D + lane] = o;
}

// ---------- Phase 2a: init x (user part) and acc = x ----------
__global__ void init_kernel(const float* __restrict__ user_emb,
                            float* __restrict__ x, float* __restrict__ acc,
                            int UD, int ND) {
    for (int idx = blockIdx.x * blockDim.x + threadIdx.x; idx < ND;
         idx += gridDim.x * blockDim.x) {
        float v = (idx < UD) ? user_emb[idx] : x[idx];
        x[idx] = v;
        acc[idx] = v;
    }
}

// ---------- CSR build: histogram ----------
__global__ void hist_kernel(const int* __restrict__ rows, int* __restrict__ cnt, int n_edges) {
    for (int e = blockIdx.x * blockDim.x + threadIdx.x; e < n_edges;
         e += gridDim.x * blockDim.x)
        atomicAdd(&cnt[rows[e]], 1);
}

// ---------- CSR build: block-level exclusive scan (chunk = 256) ----------
__global__ void scan1_kernel(const int* __restrict__ cnt, int* __restrict__ excl,
                             int* __restrict__ bsum, int N) {
    __shared__ int tmp[256];
    int tid = threadIdx.x;
    int i = blockIdx.x * 256 + tid;
    int v = (i < N) ? cnt[i] : 0;
    tmp[tid] = v;
    __syncthreads();
    for (int off = 1; off < 256; off <<= 1) {
        int t = (tid >= off) ? tmp[tid - off] : 0;
        __syncthreads();
        tmp[tid] += t;
        __syncthreads();
    }
    if (i < N) excl[i] = tmp[tid] - v;
    if (tid == 255) bsum[blockIdx.x] = tmp[tid];
}

// ---------- CSR build: scan of block sums (single block, nb <= 1024) ----------
__global__ void scan2_kernel(int* __restrict__ bsum, int nb) {
    __shared__ int tmp[1024];
    int tid = threadIdx.x;
    int v = (tid < nb) ? bsum[tid] : 0;
    tmp[tid] = v;
    __syncthreads();
    for (int off = 1; off < 1024; off <<= 1) {
        int t = (tid >= off) ? tmp[tid - off] : 0;
        __syncthreads();
        tmp[tid] += t;
        __syncthreads();
    }
    if (tid < nb) bsum[tid] = tmp[tid] - v;   // exclusive
}

// ---------- CSR build: add block offsets -> row_start, copy to fill_ptr ----------
__global__ void scan3_kernel(int* __restrict__ excl, const int* __restrict__ bsum,
                             int* __restrict__ fill_ptr, int N) {
    int i = blockIdx.x * 256 + threadIdx.x;
    if (i >= N) return;
    int v = excl[i] + bsum[blockIdx.x];
    excl[i] = v;        // excl becomes row_start
    fill_ptr[i] = v;
}

// ---------- CSR build: scatter edges into row-sorted order ----------
__global__ void fill_kernel(const int* __restrict__ rows, const int* __restrict__ cols,
                            const float* __restrict__ vals,
                            int* __restrict__ fill_ptr, int2* __restrict__ edges,
                            int n_edges) {
    for (int e = blockIdx.x * blockDim.x + threadIdx.x; e < n_edges;
         e += gridDim.x * blockDim.x) {
        int r = rows[e];
        int pos = atomicAdd(&fill_ptr[r], 1);
        edges[pos] = make_int2(cols[e], __float_as_int(vals[e]));
    }
}

// ---------- Phase 2b: CSR SpMV, one wave per row, fused acc += ----------
__global__ void spmv_kernel(const int2* __restrict__ edges, const int* __restrict__ row_start,
                            const int* __restrict__ cnt,
                            const float* __restrict__ x, float* __restrict__ nxt,
                            float* __restrict__ acc, int N) {
    long gid = (long)blockIdx.x * blockDim.x + threadIdx.x;
    int row = (int)(gid >> 6);
    int lane = (int)(gid & 63);
    if (row >= N) return;
    int s = row_start[row];
    int n = cnt[row];
    const int2* ep = edges + s;
    float sum = 0.f;
    int e = 0;
    for (; e + 4 <= n; e += 4) {
        int2 p0 = ep[e], p1 = ep[e + 1], p2 = ep[e + 2], p3 = ep[e + 3];
        sum += __int_as_float(p0.y) * x[(long)p0.x * D + lane];
        sum += __int_as_float(p1.y) * x[(long)p1.x * D + lane];
        sum += __int_as_float(p2.y) * x[(long)p2.x * D + lane];
        sum += __int_as_float(p3.y) * x[(long)p3.x * D + lane];
    }
    for (; e < n; ++e) {
        int2 p = ep[e];
        sum += __int_as_float(p.y) * x[(long)p.x * D + lane];
    }
    long o = (long)row * D + lane;
    nxt[o] = sum;
    acc[o] += sum;
}

// ---------- Phase 3: gamma[b] = dot(light[u], light[U+i]) ----------
__global__ void dot_kernel(const float* __restrict__ acc,
                           const int* __restrict__ users, const int* __restrict__ items,
                           float* __restrict__ out, int U, int B) {
    int wave = (blockIdx.x * blockDim.x + threadIdx.x) >> 6;
    int lane = threadIdx.x & 63;
    if (wave >= B) return;
    int u = users[wave];
    int it = items[wave];
    float p = acc[(long)u * D + lane] * acc[(long)(U + it) * D + lane];
    #pragma unroll
    for (int off = 32; off > 0; off >>= 1) p += __shfl_xor(p, off, 64);
    if (lane == 0) out[wave] = p * 0.0625f;
}

extern "C" void kernel_launch(void* const* d_in, const int* in_sizes, int n_in,
                              void* d_out, int out_size, void* d_ws, size_t ws_size,
                              hipStream_t stream) {
    const int*   users    = (const int*)  d_in[0];
    const int*   items    = (const int*)  d_in[1];
    const int*   g_rows   = (const int*)  d_in[2];
    const int*   g_cols   = (const int*)  d_in[3];
    const float* g_vals   = (const float*)d_in[4];
    const float* user_emb = (const float*)d_in[5];
    const float* item_emb = (const float*)d_in[6];
    const float* ent_emb  = (const float*)d_in[7];
    const float* rel_emb  = (const float*)d_in[8];
    const int*   kg_e     = (const int*)  d_in[9];
    const int*   kg_r     = (const int*)  d_in[10];
    const float* fc_W     = (const float*)d_in[11];
    const float* fc_b     = (const float*)d_in[12];
    float* out = (float*)d_out;

    int B       = in_sizes[0];
    int n_edges = in_sizes[2];
    int U       = in_sizes[5] / D;
    int I       = in_sizes[6] / D;
    int NE1     = in_sizes[7] / D;   // E_ENT + 1
    int NR      = in_sizes[8] / D;   // R + 1
    int K       = in_sizes[9] / I;
    int N  = U + I;
    int ND = N * D;
    int nb = (N + 255) / 256;        // scan blocks (must be <= 1024)

    // ---- workspace layout (256B-aligned chunks) ----
    char* base = (char*)d_ws;
    size_t off = 0;
    auto alloc = [&](size_t bytes) -> char* {
        char* p = base + off;
        off = (off + bytes + 255) & ~(size_t)255;
        return p;
    };
    float* x        = (float*)alloc((size_t)ND * 4);
    float* y        = (float*)alloc((size_t)ND * 4);
    float* acc      = (float*)alloc((size_t)ND * 4);
    float* w1r      = (float*)alloc((size_t)NR * D * 4);
    float* w2r      = (float*)alloc((size_t)NR * D * 4);
    float* br       = (float*)alloc((size_t)NR * 4);
    int*   cnt      = (int*)  alloc((size_t)N * 4);
    int*   row_start= (int*)  alloc((size_t)N * 4);
    int*   bsum     = (int*)  alloc((size_t)1024 * 4);
    int*   fill_ptr = (int*)  alloc((size_t)N * 4);
    int2*  edges    = (int2*) alloc((size_t)n_edges * 8);

    // Phase 0: relation precompute
    relpre_kernel<<<NR, D, 0, stream>>>(fc_W, fc_b, rel_emb, w1r, w2r, br);

    // Phase 1: GAT item embeddings -> item part of x
    gat_kernel<<<(I + 3) / 4, 256, 0, stream>>>(item_emb, ent_emb, kg_e, kg_r,
                                                w1r, w2r, br,
                                                x + (long)U * D, I, K, NE1 - 1);

    // Phase 2 pre: CSR build
    hipMemsetAsync(cnt, 0, (size_t)N * 4, stream);
    hist_kernel<<<2048, 256, 0, stream>>>(g_rows, cnt, n_edges);
    scan1_kernel<<<nb, 256, 0, stream>>>(cnt, row_start, bsum, N);
    scan2_kernel<<<1, 1024, 0, stream>>>(bsum, nb);
    scan3_kernel<<<nb, 256, 0, stream>>>(row_start, bsum, fill_ptr, N);
    fill_kernel<<<2048, 256, 0, stream>>>(g_rows, g_cols, g_vals, fill_ptr, edges, n_edges);

    // Phase 2a: init
    init_kernel<<<2048, 256, 0, stream>>>(user_emb, x, acc, U * D, ND);

    // Phase 2b/c: 3 LightGCN layers (no atomics)
    float* cur = x;
    float* nxt = y;
    for (int l = 0; l < 3; ++l) {
        long total = (long)N * 64;
        int blocks = (int)((total + 255) / 256);
        spmv_kernel<<<blocks, 256, 0, stream>>>(edges, row_start, cnt, cur, nxt, acc, N);
        float* t = cur; cur = nxt; nxt = t;
    }

    // Phase 3: batch dot
    dot_kernel<<<(B + 3) / 4, 256, 0, stream>>>(acc, users, items, out, U, B);
}